// Round 2
// baseline (1842.237 us; speedup 1.0000x reference)
//
#include <hip/hip_runtime.h>

#define T_STEPS 512
#define BATCH   2048
#define ISZ     128
#define HSZ     64
#define VSZ     128
#define ZSZ     192   // I + H

#define MBLK    8     // batch rows per block -> 256 blocks
#define NTHREADS 256  // 4 waves
// z_lds row: x[0:128] | hA[128:192] | hB[192:256] | pad[256:264]
#define ZLD     264

typedef __attribute__((ext_vector_type(8))) short bf16x8;
typedef __attribute__((ext_vector_type(4))) float f32x4;
typedef __attribute__((ext_vector_type(4))) unsigned short u16x4;

__device__ __forceinline__ unsigned short f2bf(float x) {
  union { float f; unsigned int u; } v; v.f = x;
  unsigned int u = v.u;
  unsigned int r = (u + 0x7fffu + ((u >> 16) & 1u)) >> 16;  // RNE
  return (unsigned short)r;
}

__device__ __forceinline__ float fsigmoid(float x) {
  return 1.0f / (1.0f + __expf(-x));
}

__device__ __forceinline__ float ftanh(float x) {
  x = fminf(fmaxf(x, -15.0f), 15.0f);
  float e = __expf(-2.0f * x);
  return (1.0f - e) / (1.0f + e);
}

__global__ __launch_bounds__(NTHREADS, 1) void lstm_kernel(
    const float* __restrict__ x,
    const float* __restrict__ h0,
    const float* __restrict__ c0,
    const float* __restrict__ Wf,  const float* __restrict__ bf_,
    const float* __restrict__ Wif, const float* __restrict__ bif_,
    const float* __restrict__ Wic, const float* __restrict__ bic_,
    const float* __restrict__ Wo,  const float* __restrict__ bo_,
    const float* __restrict__ Wout, const float* __restrict__ bout_,
    float* __restrict__ out)
{
  __shared__ unsigned short z_lds[16 * ZLD];

  const int tid  = threadIdx.x;
  const int wv   = tid >> 6;     // 0..3: owns h-cols [16w, 16w+16)
  const int ln   = tid & 63;
  const int lrow = ln & 15;
  const int lkg  = ln >> 4;      // k-group / row-group
  const int b0   = blockIdx.x * MBLK;
  const int hcol = 16 * wv + lrow;

  // ---- one-time: weight fragments into registers ----
  const float* Wg_[4] = {Wf, Wif, Wic, Wo};
  const float* bg_[4] = {bf_, bif_, bic_, bo_};

  // gate weights: this wave's 16 h-cols, all 4 gates, K=192
  bf16x8 fragWg[4][6];
#pragma unroll
  for (int g = 0; g < 4; ++g) {
#pragma unroll
    for (int kf = 0; kf < 6; ++kf) {
      const float* p = Wg_[g] + hcol * ZSZ + kf * 32 + 8 * lkg;
      bf16x8 tfr;
#pragma unroll
      for (int e = 0; e < 8; ++e) tfr[e] = (short)f2bf(p[e]);
      fragWg[g][kf] = tfr;
    }
  }
  float biasG[4];
#pragma unroll
  for (int g = 0; g < 4; ++g) biasG[g] = bg_[g][hcol];

  // out-proj weights, transposed use: A-operand = Wout rows (logit cols)
  bf16x8 fragWo[8][2];
#pragma unroll
  for (int rf = 0; rf < 8; ++rf) {
#pragma unroll
    for (int kf = 0; kf < 2; ++kf) {
      const float* p = Wout + (16 * rf + lrow) * HSZ + kf * 32 + 8 * lkg;
      bf16x8 tfr;
#pragma unroll
      for (int e = 0; e < 8; ++e) tfr[e] = (short)f2bf(p[e]);
      fragWo[rf][kf] = tfr;
    }
  }
  // out bias: C[i=16rf+4lkg+e][j], so per lane a f32x4 per rf
  f32x4 boV[8];
#pragma unroll
  for (int rf = 0; rf < 8; ++rf) boV[rf] = *(const f32x4*)&bout_[16 * rf + 4 * lkg];

  // ---- c state in registers: rows 4lkg+e, col hcol ----
  float cst[4];
#pragma unroll
  for (int e = 0; e < 4; ++e) {
    int r = 4 * lkg + e;
    cst[e] = (r < MBLK) ? c0[(b0 + r) * HSZ + hcol] : 0.0f;
  }

  // ---- zero LDS (rows 8..15 stay zero forever), then stage h0 ----
  for (int i = tid; i < 16 * ZLD; i += NTHREADS) z_lds[i] = 0;
  __syncthreads();
  {
    int idx = tid * 2;           // 512 elems = 8 rows x 64
    int r = idx >> 6, k = idx & 63;
    z_lds[r * ZLD + ISZ + k]     = f2bf(h0[(b0 + r) * HSZ + k]);
    z_lds[r * ZLD + ISZ + k + 1] = f2bf(h0[(b0 + r) * HSZ + k + 1]);
  }
  // visibility of h0 writes is covered by bar1 inside the loop

  // ---- prefetch x[0] ----
  const int xrow = tid >> 5;     // 0..7
  const int xc4  = tid & 31;
  f32x4 xr = *(const f32x4*)&x[(size_t)(b0 + xrow) * ISZ + xc4 * 4];

  const size_t probs_elems = (size_t)T_STEPS * BATCH * VSZ;

  for (int t = 0; t < T_STEPS; ++t) {
    // stage x[t]
    {
      u16x4 pk;
      pk[0] = f2bf(xr[0]); pk[1] = f2bf(xr[1]);
      pk[2] = f2bf(xr[2]); pk[3] = f2bf(xr[3]);
      *(u16x4*)&z_lds[xrow * ZLD + xc4 * 4] = pk;
    }
    __syncthreads();   // (1) z ready: x just staged, h staged before prev bar2/bar1

    // prefetch x[t+1] under compute
    if (t + 1 < T_STEPS) {
      xr = *(const f32x4*)&x[(size_t)(t + 1) * BATCH * ISZ +
                             (size_t)(b0 + xrow) * ISZ + xc4 * 4];
    }

    const int hcur = ISZ + (t & 1) * HSZ;
    const int hnxt = ISZ + ((t + 1) & 1) * HSZ;

    // ---- gate GEMM: all 4 gates for this wave's 16 h-cols ----
    f32x4 acc[4];
#pragma unroll
    for (int g = 0; g < 4; ++g) acc[g] = (f32x4){biasG[g], biasG[g], biasG[g], biasG[g]};
#pragma unroll
    for (int kf = 0; kf < 4; ++kf) {   // x part
      const bf16x8 a = *(const bf16x8*)&z_lds[lrow * ZLD + kf * 32 + 8 * lkg];
#pragma unroll
      for (int g = 0; g < 4; ++g)
        acc[g] = __builtin_amdgcn_mfma_f32_16x16x32_bf16(a, fragWg[g][kf], acc[g], 0, 0, 0);
    }
#pragma unroll
    for (int kf = 0; kf < 2; ++kf) {   // h part (current buffer)
      const bf16x8 a = *(const bf16x8*)&z_lds[lrow * ZLD + hcur + kf * 32 + 8 * lkg];
#pragma unroll
      for (int g = 0; g < 4; ++g)
        acc[g] = __builtin_amdgcn_mfma_f32_16x16x32_bf16(a, fragWg[4 + kf >= 4 ? g : g][4 + kf], acc[g], 0, 0, 0);
    }

    // ---- cell update: fully in-lane ----
    const bool last = (t == T_STEPS - 1);
#pragma unroll
    for (int e = 0; e < 4; ++e) {
      float fg = fsigmoid(acc[0][e]);
      float ig = fsigmoid(acc[1][e]);
      float cd = ftanh(acc[2][e]);
      float og = fsigmoid(acc[3][e]);
      float c  = cst[e] * fg + cd * ig;
      cst[e] = c;
      float h = ftanh(c) * og;
      int r = 4 * lkg + e;
      z_lds[r * ZLD + hnxt + hcol] = f2bf(h);
      if (last && r < MBLK) {
        out[probs_elems + (size_t)(b0 + r) * HSZ + hcol] = h;
        out[probs_elems + (size_t)BATCH * HSZ + (size_t)(b0 + r) * HSZ + hcol] = c;
      }
    }
    __syncthreads();   // (2) h[t] ready in buffer hnxt

    // ---- out-proj (transposed): C[logit][batch], batch = lane&15 ----
    const bf16x8 hb0 = *(const bf16x8*)&z_lds[lrow * ZLD + hnxt + 8 * lkg];
    const bf16x8 hb1 = *(const bf16x8*)&z_lds[lrow * ZLD + hnxt + 32 + 8 * lkg];
    f32x4 lac[8];
#pragma unroll
    for (int rf = 0; rf < 8; ++rf) {
      lac[rf] = boV[rf];
      lac[rf] = __builtin_amdgcn_mfma_f32_16x16x32_bf16(fragWo[rf][0], hb0, lac[rf], 0, 0, 0);
      lac[rf] = __builtin_amdgcn_mfma_f32_16x16x32_bf16(fragWo[rf][1], hb1, lac[rf], 0, 0, 0);
    }

    // ---- softmax in-wave: this lane holds 32 of 128 logits for batch row lrow
    float m = -1e30f;
#pragma unroll
    for (int rf = 0; rf < 8; ++rf)
#pragma unroll
      for (int e = 0; e < 4; ++e) m = fmaxf(m, lac[rf][e]);
    m = fmaxf(m, __shfl_xor(m, 16));
    m = fmaxf(m, __shfl_xor(m, 32));
    float s = 0.0f;
#pragma unroll
    for (int rf = 0; rf < 8; ++rf)
#pragma unroll
      for (int e = 0; e < 4; ++e) {
        float p = __expf(lac[rf][e] - m);
        lac[rf][e] = p;
        s += p;
      }
    s += __shfl_xor(s, 16);
    s += __shfl_xor(s, 32);
    const float inv = 1.0f / s;

    // each wave stores its 32-col slice (rf = 2wv, 2wv+1) for valid rows
    if (lrow < MBLK) {
      float* orow = &out[(size_t)t * BATCH * VSZ + (size_t)(b0 + lrow) * VSZ];
#pragma unroll
      for (int q = 0; q < 2; ++q) {
        int rf = 2 * wv + q;
        f32x4 pv = lac[rf] * inv;
        *(f32x4*)&orow[16 * rf + 4 * lkg] = pv;
      }
    }
    // next iteration's stage-x touches only x-part; gate reads of t+1 use hnxt
    // (written before bar2); h writes of t+1 go to the other buffer. No races.
  }
}

extern "C" void kernel_launch(void* const* d_in, const int* in_sizes, int n_in,
                              void* d_out, int out_size, void* d_ws, size_t ws_size,
                              hipStream_t stream) {
  const float* x    = (const float*)d_in[0];
  const float* h0   = (const float*)d_in[1];
  const float* c0   = (const float*)d_in[2];
  const float* Wf   = (const float*)d_in[3];
  const float* bf_  = (const float*)d_in[4];
  const float* Wif  = (const float*)d_in[5];
  const float* bif_ = (const float*)d_in[6];
  const float* Wic  = (const float*)d_in[7];
  const float* bic_ = (const float*)d_in[8];
  const float* Wo   = (const float*)d_in[9];
  const float* bo_  = (const float*)d_in[10];
  const float* Wout = (const float*)d_in[11];
  const float* bout = (const float*)d_in[12];
  float* out = (float*)d_out;

  hipLaunchKernelGGL(lstm_kernel, dim3(BATCH / MBLK), dim3(NTHREADS), 0, stream,
                     x, h0, c0, Wf, bf_, Wif, bif_, Wic, bic_, Wo, bo_, Wout, bout, out);
}

// Round 3
// 680.993 us; speedup vs baseline: 2.7052x; 2.7052x over previous
//
#include <hip/hip_runtime.h>

#define T_STEPS 512
#define BATCH   2048
#define ISZ     128
#define HSZ     64
#define VSZ     128
#define ZSZ     192   // I + H

#define MBLK    8     // batch rows per block -> 256 blocks
#define NTHREADS 384  // 4 P-waves + 2 Q-waves
#define HLD     72    // hbuf row stride in bf16 (72*2B=144B -> bank stride 4, 2-way max)

typedef __attribute__((ext_vector_type(8))) short bf16x8;
typedef __attribute__((ext_vector_type(4))) float f32x4;

#define WG_SCOPE __HIP_MEMORY_SCOPE_WORKGROUP

__device__ __forceinline__ unsigned short f2bf(float x) {
  union { float f; unsigned int u; } v; v.f = x;
  unsigned int u = v.u;
  unsigned int r = (u + 0x7fffu + ((u >> 16) & 1u)) >> 16;  // RNE
  return (unsigned short)r;
}

__device__ __forceinline__ float fsigmoid(float x) {
  return 1.0f / (1.0f + __expf(-x));
}

__device__ __forceinline__ float ftanh(float x) {
  x = fminf(fmaxf(x, -15.0f), 15.0f);
  float e = __expf(-2.0f * x);
  return (1.0f - e) / (1.0f + e);
}

__global__ __launch_bounds__(NTHREADS, 2) void lstm_kernel(
    const float* __restrict__ x,
    const float* __restrict__ h0,
    const float* __restrict__ c0,
    const float* __restrict__ Wf,  const float* __restrict__ bf_,
    const float* __restrict__ Wif, const float* __restrict__ bif_,
    const float* __restrict__ Wic, const float* __restrict__ bic_,
    const float* __restrict__ Wo,  const float* __restrict__ bo_,
    const float* __restrict__ Wout, const float* __restrict__ bout_,
    float* __restrict__ out)
{
  // 4-deep ring of h states (bf16), [slot][row][hcol]
  __shared__ unsigned short hbuf[4][16][HLD];
  __shared__ int pbar;        // monotonically counts P-wave step completions
  __shared__ int q_done[2];   // per-parity count of h slots consumed by Q

  const int tid  = threadIdx.x;
  const int wv   = tid >> 6;     // 0..3 = P, 4..5 = Q
  const int ln   = tid & 63;
  const int lrow = ln & 15;
  const int lkg  = ln >> 4;
  const int b0   = blockIdx.x * MBLK;

  if (tid == 0) { pbar = 0; q_done[0] = 0; q_done[1] = 0; }

  // stage h0 -> hbuf slot 0 (all 16 rows; rows >= MBLK clamped duplicates, finite)
  if (tid < 256) {
    int r = tid >> 4, cb = (tid & 15) * 4;
    int rr = min(b0 + r, BATCH - 1);
    f32x4 hv = *(const f32x4*)&h0[rr * HSZ + cb];
#pragma unroll
    for (int j = 0; j < 4; ++j) hbuf[0][r][cb + j] = f2bf(hv[j]);
  }
  __syncthreads();

  const size_t probs_elems = (size_t)T_STEPS * BATCH * VSZ;

  if (wv < 4) {
    // ================= P-wave: the recurrence =================
    const int hcol = 16 * wv + lrow;     // this wave's h-col for cell update
    const float* Wg_[4] = {Wf, Wif, Wic, Wo};
    const float* bg_[4] = {bf_, bif_, bic_, bo_};

    bf16x8 fragWg[4][6];                 // [gate][kf], B-operand fragments
#pragma unroll
    for (int g = 0; g < 4; ++g)
#pragma unroll
      for (int kf = 0; kf < 6; ++kf) {
        const float* p = Wg_[g] + hcol * ZSZ + kf * 32 + 8 * lkg;
        bf16x8 tfr;
#pragma unroll
        for (int e = 0; e < 8; ++e) tfr[e] = (short)f2bf(p[e]);
        fragWg[g][kf] = tfr;
      }
    float biasG[4];
#pragma unroll
    for (int g = 0; g < 4; ++g) biasG[g] = bg_[g][hcol];

    float cst[4];
#pragma unroll
    for (int e = 0; e < 4; ++e) {
      int rr = min(b0 + 4 * lkg + e, BATCH - 1);
      cst[e] = c0[rr * HSZ + hcol];
    }

    // x A-fragments live entirely in registers
    const int rowx = min(b0 + lrow, BATCH - 1);
    const int xoff = 8 * lkg;
    f32x4 xpre[4][2];
    {
      const float* xt = x + (size_t)rowx * ISZ;
#pragma unroll
      for (int kf = 0; kf < 4; ++kf) {
        xpre[kf][0] = *(const f32x4*)&xt[kf * 32 + xoff];
        xpre[kf][1] = *(const f32x4*)&xt[kf * 32 + xoff + 4];
      }
    }
    bf16x8 xfrag[4];
#pragma unroll
    for (int kf = 0; kf < 4; ++kf) {
      bf16x8 f;
#pragma unroll
      for (int j = 0; j < 8; ++j)
        f[j] = (short)f2bf(j < 4 ? xpre[kf][0][j] : xpre[kf][1][j - 4]);
      xfrag[kf] = f;
    }

    float h4[4];
    for (int t = 0; t < T_STEPS; ++t) {
      // wait for h[t] slot (all P waves finished step t-1)
      if (t)
        while (__hip_atomic_load(&pbar, __ATOMIC_ACQUIRE, WG_SCOPE) < 4 * t) {}

      // h A-fragments for this step
      const unsigned short* hrow = &hbuf[t & 3][lrow][0];
      const bf16x8 hf0 = *(const bf16x8*)&hrow[xoff];
      const bf16x8 hf1 = *(const bf16x8*)&hrow[32 + xoff];

      // issue next x loads early (latency hidden under MFMAs)
      if (t + 1 < T_STEPS) {
        const float* xt = x + (size_t)(t + 1) * BATCH * ISZ + (size_t)rowx * ISZ;
#pragma unroll
        for (int kf = 0; kf < 4; ++kf) {
          xpre[kf][0] = *(const f32x4*)&xt[kf * 32 + xoff];
          xpre[kf][1] = *(const f32x4*)&xt[kf * 32 + xoff + 4];
        }
      }

      // gate GEMM: 4 gates x (4 x-kf + 2 h-kf)
      f32x4 acc[4];
#pragma unroll
      for (int g = 0; g < 4; ++g) acc[g] = (f32x4){biasG[g], biasG[g], biasG[g], biasG[g]};
#pragma unroll
      for (int kf = 0; kf < 4; ++kf)
#pragma unroll
        for (int g = 0; g < 4; ++g)
          acc[g] = __builtin_amdgcn_mfma_f32_16x16x32_bf16(xfrag[kf], fragWg[g][kf], acc[g], 0, 0, 0);
#pragma unroll
      for (int g = 0; g < 4; ++g)
        acc[g] = __builtin_amdgcn_mfma_f32_16x16x32_bf16(hf0, fragWg[g][4], acc[g], 0, 0, 0);
#pragma unroll
      for (int g = 0; g < 4; ++g)
        acc[g] = __builtin_amdgcn_mfma_f32_16x16x32_bf16(hf1, fragWg[g][5], acc[g], 0, 0, 0);

      // cell update, fully in-lane
#pragma unroll
      for (int e = 0; e < 4; ++e) {
        float fg = fsigmoid(acc[0][e]);
        float ig = fsigmoid(acc[1][e]);
        float cd = ftanh(acc[2][e]);
        float og = fsigmoid(acc[3][e]);
        float c  = cst[e] * fg + cd * ig;
        cst[e] = c;
        h4[e] = ftanh(c) * og;
      }

      // don't overwrite an h slot Q hasn't consumed (slot (t+1)%4 holds h[t-3])
      if (t >= 4) {
        const int tgt = (t - 4) / 2 + 1;
        while (__hip_atomic_load(&q_done[t & 1], __ATOMIC_ACQUIRE, WG_SCOPE) < tgt) {}
      }

      // publish h[t+1]
#pragma unroll
      for (int e = 0; e < 4; ++e)
        hbuf[(t + 1) & 3][4 * lkg + e][hcol] = f2bf(h4[e]);
      __threadfence_block();
      if (ln == 0) __hip_atomic_fetch_add(&pbar, 1, __ATOMIC_RELEASE, WG_SCOPE);

      // convert next x fragments (vmcnt wait lands here, off critical path)
      if (t + 1 < T_STEPS) {
#pragma unroll
        for (int kf = 0; kf < 4; ++kf) {
          bf16x8 f;
#pragma unroll
          for (int j = 0; j < 8; ++j)
            f[j] = (short)f2bf(j < 4 ? xpre[kf][0][j] : xpre[kf][1][j - 4]);
          xfrag[kf] = f;
        }
      }

      if (t == T_STEPS - 1) {
#pragma unroll
        for (int e = 0; e < 4; ++e) {
          int r = 4 * lkg + e;
          if (r < MBLK) {
            out[probs_elems + (size_t)(b0 + r) * HSZ + hcol] = h4[e];
            out[probs_elems + (size_t)BATCH * HSZ + (size_t)(b0 + r) * HSZ + hcol] = cst[e];
          }
        }
      }
    }
  } else {
    // ================= Q-wave: out-proj + softmax + store =================
    const int q = wv - 4;                // parity: Q0 even t, Q1 odd t

    bf16x8 fragWo[8][2];
#pragma unroll
    for (int rf = 0; rf < 8; ++rf)
#pragma unroll
      for (int kf = 0; kf < 2; ++kf) {
        const float* p = Wout + (16 * rf + lrow) * HSZ + kf * 32 + 8 * lkg;
        bf16x8 tfr;
#pragma unroll
        for (int e = 0; e < 8; ++e) tfr[e] = (short)f2bf(p[e]);
        fragWo[rf][kf] = tfr;
      }
    f32x4 boV[8];
#pragma unroll
    for (int rf = 0; rf < 8; ++rf) boV[rf] = *(const f32x4*)&bout_[16 * rf + 4 * lkg];

    for (int t = q; t < T_STEPS; t += 2) {
      // wait until all P waves produced h[t+1]
      while (__hip_atomic_load(&pbar, __ATOMIC_ACQUIRE, WG_SCOPE) < 4 * (t + 1)) {}

      const unsigned short* hrow = &hbuf[(t + 1) & 3][lrow][0];
      const bf16x8 hb0 = *(const bf16x8*)&hrow[8 * lkg];
      const bf16x8 hb1 = *(const bf16x8*)&hrow[32 + 8 * lkg];
      __threadfence_block();   // reads complete -> safe to let P overwrite
      if (ln == 0)
        __hip_atomic_store(&q_done[q], t / 2 + 1, __ATOMIC_RELEASE, WG_SCOPE);

      // transposed out-proj: C[logit][batch], batch = lane&15
      f32x4 lac[8];
#pragma unroll
      for (int rf = 0; rf < 8; ++rf) {
        lac[rf] = boV[rf];
        lac[rf] = __builtin_amdgcn_mfma_f32_16x16x32_bf16(fragWo[rf][0], hb0, lac[rf], 0, 0, 0);
        lac[rf] = __builtin_amdgcn_mfma_f32_16x16x32_bf16(fragWo[rf][1], hb1, lac[rf], 0, 0, 0);
      }

      // softmax: lane holds 32 of 128 logits for batch row lrow
      float m = -1e30f;
#pragma unroll
      for (int rf = 0; rf < 8; ++rf)
#pragma unroll
        for (int e = 0; e < 4; ++e) m = fmaxf(m, lac[rf][e]);
      m = fmaxf(m, __shfl_xor(m, 16));
      m = fmaxf(m, __shfl_xor(m, 32));
      float s = 0.0f;
#pragma unroll
      for (int rf = 0; rf < 8; ++rf)
#pragma unroll
        for (int e = 0; e < 4; ++e) {
          float p = __expf(lac[rf][e] - m);
          lac[rf][e] = p;
          s += p;
        }
      s += __shfl_xor(s, 16);
      s += __shfl_xor(s, 32);
      const float inv = 1.0f / s;

      if (lrow < MBLK) {
        float* orow = &out[(size_t)t * BATCH * VSZ + (size_t)(b0 + lrow) * VSZ];
#pragma unroll
        for (int rf = 0; rf < 8; ++rf) {
          f32x4 pv = lac[rf] * inv;
          *(f32x4*)&orow[16 * rf + 4 * lkg] = pv;
        }
      }
    }
  }
}

extern "C" void kernel_launch(void* const* d_in, const int* in_sizes, int n_in,
                              void* d_out, int out_size, void* d_ws, size_t ws_size,
                              hipStream_t stream) {
  const float* x    = (const float*)d_in[0];
  const float* h0   = (const float*)d_in[1];
  const float* c0   = (const float*)d_in[2];
  const float* Wf   = (const float*)d_in[3];
  const float* bf_  = (const float*)d_in[4];
  const float* Wif  = (const float*)d_in[5];
  const float* bif_ = (const float*)d_in[6];
  const float* Wic  = (const float*)d_in[7];
  const float* bic_ = (const float*)d_in[8];
  const float* Wo   = (const float*)d_in[9];
  const float* bo_  = (const float*)d_in[10];
  const float* Wout = (const float*)d_in[11];
  const float* bout = (const float*)d_in[12];
  float* out = (float*)d_out;

  hipLaunchKernelGGL(lstm_kernel, dim3(BATCH / MBLK), dim3(NTHREADS), 0, stream,
                     x, h0, c0, Wf, bf_, Wif, bif_, Wic, bic_, Wo, bo_, Wout, bout, out);
}

// Round 4
// 669.167 us; speedup vs baseline: 2.7530x; 1.0177x over previous
//
#include <hip/hip_runtime.h>

#define T_STEPS 512
#define BATCH   2048
#define ISZ     128
#define HSZ     64
#define VSZ     128
#define ZSZ     192   // I + H

#define MBLK    8     // batch rows per block -> 256 blocks
#define NTHREADS 512  // 4 P-waves + 4 Q-waves (1P + 1Q per SIMD)
#define HLD     72    // hbuf row stride in bf16 (144 B = 9 x 16B, b128-aligned)

typedef __attribute__((ext_vector_type(8))) short bf16x8;
typedef __attribute__((ext_vector_type(4))) float f32x4;

#define WG_SCOPE __HIP_MEMORY_SCOPE_WORKGROUP

__device__ __forceinline__ unsigned short f2bf(float x) {
  union { float f; unsigned int u; } v; v.f = x;
  unsigned int u = v.u;
  unsigned int r = (u + 0x7fffu + ((u >> 16) & 1u)) >> 16;  // RNE
  return (unsigned short)r;
}

__device__ __forceinline__ float fsigmoid(float x) {
  return 1.0f / (1.0f + __expf(-x));
}

__device__ __forceinline__ float ftanh(float x) {
  x = fminf(fmaxf(x, -15.0f), 15.0f);
  float e = __expf(-2.0f * x);
  return (1.0f - e) / (1.0f + e);
}

__global__ __launch_bounds__(NTHREADS, 2) void lstm_kernel(
    const float* __restrict__ x,
    const float* __restrict__ h0,
    const float* __restrict__ c0,
    const float* __restrict__ Wf,  const float* __restrict__ bf_,
    const float* __restrict__ Wif, const float* __restrict__ bif_,
    const float* __restrict__ Wic, const float* __restrict__ bic_,
    const float* __restrict__ Wo,  const float* __restrict__ bo_,
    const float* __restrict__ Wout, const float* __restrict__ bout_,
    float* __restrict__ out)
{
  // 4-deep ring of h states (bf16), [slot][row][hcol]
  __shared__ unsigned short hbuf[4][16][HLD];
  __shared__ int pbar;        // counts P-wave step completions (4 per step)
  __shared__ int q_done[4];   // per-parity count of h slots consumed by Q

  const int tid  = threadIdx.x;
  const int wv   = tid >> 6;     // 0..3 = P, 4..7 = Q
  const int ln   = tid & 63;
  const int lrow = ln & 15;
  const int lkg  = ln >> 4;
  const int b0   = blockIdx.x * MBLK;

  if (tid == 0) pbar = 0;
  if (tid < 4) q_done[tid] = 0;

  // stage h0 -> hbuf slot 0 (16 rows; rows >= MBLK are clamped dupes, finite)
  if (tid < 256) {
    int r = tid >> 4, cb = (tid & 15) * 4;
    int rr = min(b0 + r, BATCH - 1);
    f32x4 hv = *(const f32x4*)&h0[rr * HSZ + cb];
#pragma unroll
    for (int j = 0; j < 4; ++j) hbuf[0][r][cb + j] = f2bf(hv[j]);
  }
  __syncthreads();

  const size_t probs_elems = (size_t)T_STEPS * BATCH * VSZ;

  if (wv < 4) {
    // ================= P-wave: the recurrence =================
    const int hcol = 16 * wv + lrow;
    const float* Wg_[4] = {Wf, Wif, Wic, Wo};
    const float* bg_[4] = {bf_, bif_, bic_, bo_};

    bf16x8 fragWg[4][6];                 // [gate][kf], B-operand fragments
#pragma unroll
    for (int g = 0; g < 4; ++g)
#pragma unroll
      for (int kf = 0; kf < 6; ++kf) {
        const float* p = Wg_[g] + hcol * ZSZ + kf * 32 + 8 * lkg;
        bf16x8 tfr;
#pragma unroll
        for (int e = 0; e < 8; ++e) tfr[e] = (short)f2bf(p[e]);
        fragWg[g][kf] = tfr;
      }
    float biasG[4];
#pragma unroll
    for (int g = 0; g < 4; ++g) biasG[g] = bg_[g][hcol];

    float cst[4];
#pragma unroll
    for (int e = 0; e < 4; ++e) {
      int rr = min(b0 + 4 * lkg + e, BATCH - 1);
      cst[e] = c0[rr * HSZ + hcol];
    }

    // ---- x pipeline: xfrag = x[t] (ready), xraw = x[t+1] (in flight) ----
    const int rowx = min(b0 + lrow, BATCH - 1);
    const int xoff = 8 * lkg;
    f32x4 xraw[4][2];
    bf16x8 xfrag[4];
    {
      const float* xt = x + (size_t)rowx * ISZ;
#pragma unroll
      for (int kf = 0; kf < 4; ++kf) {
        f32x4 a = *(const f32x4*)&xt[kf * 32 + xoff];
        f32x4 b = *(const f32x4*)&xt[kf * 32 + xoff + 4];
        bf16x8 f;
#pragma unroll
        for (int j = 0; j < 4; ++j) { f[j] = (short)f2bf(a[j]); f[4 + j] = (short)f2bf(b[j]); }
        xfrag[kf] = f;
      }
      const float* xn = x + (size_t)BATCH * ISZ + (size_t)rowx * ISZ;
#pragma unroll
      for (int kf = 0; kf < 4; ++kf) {
        xraw[kf][0] = *(const f32x4*)&xn[kf * 32 + xoff];
        xraw[kf][1] = *(const f32x4*)&xn[kf * 32 + xoff + 4];
      }
    }

    float h4[4];
    for (int t = 0; t < T_STEPS; ++t) {
      // (a) x-part MFMAs — independent of h, issue BEFORE the spin
      f32x4 acc[4];
#pragma unroll
      for (int g = 0; g < 4; ++g) acc[g] = (f32x4){biasG[g], biasG[g], biasG[g], biasG[g]};
#pragma unroll
      for (int kf = 0; kf < 4; ++kf)
#pragma unroll
        for (int g = 0; g < 4; ++g)
          acc[g] = __builtin_amdgcn_mfma_f32_16x16x32_bf16(xfrag[kf], fragWg[g][kf], acc[g], 0, 0, 0);
      __builtin_amdgcn_sched_barrier(0);   // keep x-MFMAs above the spin

      // (b) wait for h[t] (all P waves finished step t-1)
      if (t)
        while (__hip_atomic_load(&pbar, __ATOMIC_ACQUIRE, WG_SCOPE) < 4 * t) {}

      // (c) h fragments + 8 MFMAs
      const unsigned short* hrow = &hbuf[t & 3][lrow][0];
      const bf16x8 hf0 = *(const bf16x8*)&hrow[xoff];
      const bf16x8 hf1 = *(const bf16x8*)&hrow[32 + xoff];
#pragma unroll
      for (int g = 0; g < 4; ++g)
        acc[g] = __builtin_amdgcn_mfma_f32_16x16x32_bf16(hf0, fragWg[g][4], acc[g], 0, 0, 0);
#pragma unroll
      for (int g = 0; g < 4; ++g)
        acc[g] = __builtin_amdgcn_mfma_f32_16x16x32_bf16(hf1, fragWg[g][5], acc[g], 0, 0, 0);

      // (d) cell update, fully in-lane
#pragma unroll
      for (int e = 0; e < 4; ++e) {
        float fg = fsigmoid(acc[0][e]);
        float ig = fsigmoid(acc[1][e]);
        float cd = ftanh(acc[2][e]);
        float og = fsigmoid(acc[3][e]);
        float c  = cst[e] * fg + cd * ig;
        cst[e] = c;
        h4[e] = ftanh(c) * og;
      }

      // (e) ring safety: slot (t+1)&3 holds h[t-3], consumed by Q_{(t-4)&3}
      if (t >= 4) {
        const int u = t - 4;
        while (__hip_atomic_load(&q_done[u & 3], __ATOMIC_ACQUIRE, WG_SCOPE) < u / 4 + 1) {}
      }

      // (f) publish h[t+1]
#pragma unroll
      for (int e = 0; e < 4; ++e)
        hbuf[(t + 1) & 3][4 * lkg + e][hcol] = f2bf(h4[e]);
      __threadfence_block();
      if (ln == 0) __hip_atomic_fetch_add(&pbar, 1, __ATOMIC_RELEASE, WG_SCOPE);

      // (g) convert x[t+1] (loads issued one full step ago -> vmcnt wait ~0)
      if (t + 1 < T_STEPS) {
#pragma unroll
        for (int kf = 0; kf < 4; ++kf) {
          bf16x8 f;
#pragma unroll
          for (int j = 0; j < 4; ++j) {
            f[j]     = (short)f2bf(xraw[kf][0][j]);
            f[4 + j] = (short)f2bf(xraw[kf][1][j]);
          }
          xfrag[kf] = f;
        }
      }
      // (h) issue loads for x[t+2]
      if (t + 2 < T_STEPS) {
        const float* xn = x + (size_t)(t + 2) * BATCH * ISZ + (size_t)rowx * ISZ;
#pragma unroll
        for (int kf = 0; kf < 4; ++kf) {
          xraw[kf][0] = *(const f32x4*)&xn[kf * 32 + xoff];
          xraw[kf][1] = *(const f32x4*)&xn[kf * 32 + xoff + 4];
        }
      }

      if (t == T_STEPS - 1) {
#pragma unroll
        for (int e = 0; e < 4; ++e) {
          int r = 4 * lkg + e;
          if (r < MBLK) {
            out[probs_elems + (size_t)(b0 + r) * HSZ + hcol] = h4[e];
            out[probs_elems + (size_t)BATCH * HSZ + (size_t)(b0 + r) * HSZ + hcol] = cst[e];
          }
        }
      }
    }
  } else {
    // ================= Q-wave: out-proj + softmax + store =================
    const int q = wv - 4;                // handles t === q (mod 4)

    bf16x8 fragWo[8][2];
#pragma unroll
    for (int rf = 0; rf < 8; ++rf)
#pragma unroll
      for (int kf = 0; kf < 2; ++kf) {
        const float* p = Wout + (16 * rf + lrow) * HSZ + kf * 32 + 8 * lkg;
        bf16x8 tfr;
#pragma unroll
        for (int e = 0; e < 8; ++e) tfr[e] = (short)f2bf(p[e]);
        fragWo[rf][kf] = tfr;
      }
    f32x4 boV[8];
#pragma unroll
    for (int rf = 0; rf < 8; ++rf) boV[rf] = *(const f32x4*)&bout_[16 * rf + 4 * lkg];

    for (int t = q; t < T_STEPS; t += 4) {
      // wait until all P waves produced h[t+1]
      while (__hip_atomic_load(&pbar, __ATOMIC_ACQUIRE, WG_SCOPE) < 4 * (t + 1)) {}

      const unsigned short* hrow = &hbuf[(t + 1) & 3][lrow][0];
      const bf16x8 hb0 = *(const bf16x8*)&hrow[8 * lkg];
      const bf16x8 hb1 = *(const bf16x8*)&hrow[32 + 8 * lkg];
      __threadfence_block();   // reads retired -> safe to let P overwrite
      if (ln == 0)
        __hip_atomic_store(&q_done[q], t / 4 + 1, __ATOMIC_RELEASE, WG_SCOPE);

      // transposed out-proj: C[logit][batch], batch = lane&15
      f32x4 lac[8];
#pragma unroll
      for (int rf = 0; rf < 8; ++rf) {
        lac[rf] = boV[rf];
        lac[rf] = __builtin_amdgcn_mfma_f32_16x16x32_bf16(fragWo[rf][0], hb0, lac[rf], 0, 0, 0);
        lac[rf] = __builtin_amdgcn_mfma_f32_16x16x32_bf16(fragWo[rf][1], hb1, lac[rf], 0, 0, 0);
      }

      // softmax: lane holds 32 of 128 logits for batch row lrow
      float m = -1e30f;
#pragma unroll
      for (int rf = 0; rf < 8; ++rf)
#pragma unroll
        for (int e = 0; e < 4; ++e) m = fmaxf(m, lac[rf][e]);
      m = fmaxf(m, __shfl_xor(m, 16));
      m = fmaxf(m, __shfl_xor(m, 32));
      float s = 0.0f;
#pragma unroll
      for (int rf = 0; rf < 8; ++rf)
#pragma unroll
        for (int e = 0; e < 4; ++e) {
          float p = __expf(lac[rf][e] - m);
          lac[rf][e] = p;
          s += p;
        }
      s += __shfl_xor(s, 16);
      s += __shfl_xor(s, 32);
      const float inv = 1.0f / s;

      if (lrow < MBLK) {
        float* orow = &out[(size_t)t * BATCH * VSZ + (size_t)(b0 + lrow) * VSZ];
#pragma unroll
        for (int rf = 0; rf < 8; ++rf) {
          f32x4 pv = lac[rf] * inv;
          *(f32x4*)&orow[16 * rf + 4 * lkg] = pv;
        }
      }
    }
  }
}

extern "C" void kernel_launch(void* const* d_in, const int* in_sizes, int n_in,
                              void* d_out, int out_size, void* d_ws, size_t ws_size,
                              hipStream_t stream) {
  const float* x    = (const float*)d_in[0];
  const float* h0   = (const float*)d_in[1];
  const float* c0   = (const float*)d_in[2];
  const float* Wf   = (const float*)d_in[3];
  const float* bf_  = (const float*)d_in[4];
  const float* Wif  = (const float*)d_in[5];
  const float* bif_ = (const float*)d_in[6];
  const float* Wic  = (const float*)d_in[7];
  const float* bic_ = (const float*)d_in[8];
  const float* Wo   = (const float*)d_in[9];
  const float* bo_  = (const float*)d_in[10];
  const float* Wout = (const float*)d_in[11];
  const float* bout = (const float*)d_in[12];
  float* out = (float*)d_out;

  hipLaunchKernelGGL(lstm_kernel, dim3(BATCH / MBLK), dim3(NTHREADS), 0, stream,
                     x, h0, c0, Wf, bf_, Wif, bif_, Wic, bic_, Wo, bo_, Wout, bout, out);
}